// Round 5
// baseline (103.835 us; speedup 1.0000x reference)
//
#include <hip/hip_runtime.h>
#include <hip/hip_bf16.h>
#include <math.h>

#define HD 256
#define BB 64
#define DD 2048
#define NCHK 8          // d-chunks per batch (256 rows each)
#define NT 8            // 32-row tiles per chunk

typedef __attribute__((ext_vector_type(8))) short  short8;
typedef __attribute__((ext_vector_type(4))) float  float4v;
typedef __attribute__((ext_vector_type(4))) unsigned short ushort4v;

__device__ inline unsigned short f2bf(float f) {
    unsigned u = __builtin_bit_cast(unsigned, f);
    u += 0x7FFFu + ((u >> 16) & 1u);   // RNE
    return (unsigned short)(u >> 16);
}
__device__ inline float bf2f(unsigned short u) {
    return __builtin_bit_cast(float, (unsigned)u << 16);
}

__device__ inline float fast_exp2(float x) {
    float r;
    asm("v_exp_f32 %0, %1" : "=v"(r) : "v"(x));
    return r;
}
__device__ inline float fast_expf(float x) { return fast_exp2(x * 1.4426950408889634f); }
__device__ inline float fast_tanh(float x) {
    float y = x * 2.8853900817779268f;          // 2x * log2(e)
    y = fminf(fmaxf(y, -30.f), 30.f);
    float t = fast_exp2(y);
    float r;
    asm("v_rcp_f32 %0, %1" : "=v"(r) : "v"(t + 1.f));
    return (t - 1.f) * r;
}

// ---------------- kernel 0 (fused prep): W1 f32->bf16  AND  g23 ----------------
__global__ __launch_bounds__(256) void k_prep(const float* __restrict__ W1,
                                              unsigned short* __restrict__ w1b,
                                              const float* __restrict__ ctx,
                                              const float* __restrict__ hid,
                                              const float* __restrict__ W2,
                                              const float* __restrict__ b2,
                                              const float* __restrict__ W3,
                                              float* __restrict__ g23) {
    if (blockIdx.x < 64) {
        int i = blockIdx.x * 256 + threadIdx.x;
        float4v v = ((const float4v*)W1)[i];
        ushort4v o;
        o[0] = f2bf(v[0]); o[1] = f2bf(v[1]); o[2] = f2bf(v[2]); o[3] = f2bf(v[3]);
        ((ushort4v*)w1b)[i] = o;
    } else {
        int b = blockIdx.x - 64, t = threadIdx.x;
        __shared__ float c[HD], hh[HD];
        c[t]  = ctx[b * HD + t];
        hh[t] = hid[b * HD + t];
        __syncthreads();
        const float4v* w2 = (const float4v*)(W2 + (size_t)t * HD);
        const float4v* w3 = (const float4v*)(W3 + (size_t)t * HD);
        float acc = b2[t];
        #pragma unroll 8
        for (int k = 0; k < 64; ++k) {
            float4v a = w2[k], d = w3[k];
            int k4 = k * 4;
            acc += c[k4] * a[0] + c[k4 + 1] * a[1] + c[k4 + 2] * a[2] + c[k4 + 3] * a[3];
            acc += hh[k4] * d[0] + hh[k4 + 1] * d[1] + hh[k4 + 2] * d[2] + hh[k4 + 3] * d[3];
        }
        g23[b * HD + t] = acc;
    }
}

// ---------------- kernel 1: flash-style fused scores+softmax+PV ----------------
// grid (8, 64), 512 thr (8 waves). Wave owns 32 h-cols (W1 slice in 64 VGPRs).
// Per 32-row tile: stage f32->bf16 LDS (swizzled) -> swapped MFMA C[h][d] ->
// tanh.W4 + 2-shfl h-reduce -> online softmax + PV from bf16 tile.
__global__ __launch_bounds__(512, 4) void k_fused(const float* __restrict__ q,
                                                  const unsigned short* __restrict__ w1b,
                                                  const float* __restrict__ g23,
                                                  const float* __restrict__ W4,
                                                  float* __restrict__ pstats,
                                                  float* __restrict__ pO) {
    __shared__ __attribute__((aligned(16))) unsigned short tile[32 * HD]; // 16 KB
    __shared__ float sp[8][32];
    __shared__ float sp2[33];
    __shared__ float spO[256];
    __shared__ float spl[1];

    const int t = threadIdx.x;
    const int chunk = blockIdx.x, b = blockIdx.y;
    const int lane = t & 63, wave = t >> 6;
    const int l15 = lane & 15, lk = lane >> 4;
    const int hb = wave * 32;

    const float* qc = q + ((size_t)(b * DD + chunk * 256)) * HD;

    // staging geometry: thread covers row sr, 16 f32 at col sc
    const int sr = t >> 4, sc = (t & 15) * 16;

    float4v st0, st1, st2, st3;
    {
        const float4v* src = (const float4v*)(qc + (size_t)sr * HD + sc);
        st0 = src[0]; st1 = src[1]; st2 = src[2]; st3 = src[3];
    }

    // W1 slice (A operand) -> 64 VGPR
    short8 bfr[8][2];
    #pragma unroll
    for (int kb = 0; kb < 8; ++kb)
        #pragma unroll
        for (int nf = 0; nf < 2; ++nf)
            bfr[kb][nf] = *(const short8*)&w1b[(size_t)(hb + nf * 16 + l15) * HD + kb * 32 + lk * 8];

    // per-lane g23/W4 for C rows h = hb + nf*16 + lk*4 + r
    float gv[2][4], wv[2][4];
    #pragma unroll
    for (int nf = 0; nf < 2; ++nf)
        #pragma unroll
        for (int r = 0; r < 4; ++r) {
            int h = hb + nf * 16 + lk * 4 + r;
            gv[nf][r] = g23[b * HD + h];
            wv[nf][r] = W4[h];
        }

    float m = -1e30f, l = 0.f, Ot = 0.f;
    const int pc = t & 255;          // PV column
    const int dh = (t >> 8) * 16;    // PV d-half

    for (int tt = 0; tt < NT; ++tt) {
        __syncthreads();   // (A) prev online update done reading tile
        // convert + swizzled store
        {
            short8 p0, p1;
            p0[0] = (short)f2bf(st0[0]); p0[1] = (short)f2bf(st0[1]);
            p0[2] = (short)f2bf(st0[2]); p0[3] = (short)f2bf(st0[3]);
            p0[4] = (short)f2bf(st1[0]); p0[5] = (short)f2bf(st1[1]);
            p0[6] = (short)f2bf(st1[2]); p0[7] = (short)f2bf(st1[3]);
            p1[0] = (short)f2bf(st2[0]); p1[1] = (short)f2bf(st2[1]);
            p1[2] = (short)f2bf(st2[2]); p1[3] = (short)f2bf(st2[3]);
            p1[4] = (short)f2bf(st3[0]); p1[5] = (short)f2bf(st3[1]);
            p1[6] = (short)f2bf(st3[2]); p1[7] = (short)f2bf(st3[3]);
            int base = sr * 512 + sc * 2;        // bytes
            int sw = (sr & 7) << 4;
            *(short8*)((char*)tile + ((base) ^ sw))      = p0;
            *(short8*)((char*)tile + ((base + 16) ^ sw)) = p1;
        }
        __syncthreads();   // (B) tile ready (ds ops only)

        // T14: issue next tile's loads now; they fly under MFMA+epilogue
        if (tt + 1 < NT) {
            const float4v* src = (const float4v*)(qc + (size_t)(tt + 1) * 32 * HD + (size_t)sr * HD + sc);
            st0 = src[0]; st1 = src[1]; st2 = src[2]; st3 = src[3];
        }

        // MFMA: C[h][d] = sum_k W1[h][k] q[d][k]
        float4v acc[2][2];
        #pragma unroll
        for (int df = 0; df < 2; ++df)
            #pragma unroll
            for (int nf = 0; nf < 2; ++nf)
                acc[df][nf] = (float4v){0.f, 0.f, 0.f, 0.f};

        #pragma unroll
        for (int kb = 0; kb < 8; ++kb) {
            short8 bq[2];
            #pragma unroll
            for (int df = 0; df < 2; ++df) {
                int d = df * 16 + l15;
                int byte = d * 512 + kb * 64 + lk * 16;
                bq[df] = *(const short8*)((const char*)tile + (byte ^ ((d & 7) << 4)));
            }
            #pragma unroll
            for (int nf = 0; nf < 2; ++nf) {
                acc[0][nf] = __builtin_amdgcn_mfma_f32_16x16x32_bf16(bfr[kb][nf], bq[0], acc[0][nf], 0, 0, 0);
                acc[1][nf] = __builtin_amdgcn_mfma_f32_16x16x32_bf16(bfr[kb][nf], bq[1], acc[1][nf], 0, 0, 0);
            }
        }

        // epilogue: tanh + W4, reduce over h (VALU over nf,r; shfl over lk)
        #pragma unroll
        for (int df = 0; df < 2; ++df) {
            float s = 0.f;
            #pragma unroll
            for (int nf = 0; nf < 2; ++nf)
                #pragma unroll
                for (int r = 0; r < 4; ++r)
                    s += fast_tanh(acc[df][nf][r] + gv[nf][r]) * wv[nf][r];
            s += __shfl_xor(s, 16, 64);
            s += __shfl_xor(s, 32, 64);
            if (lk == 0) sp[wave][df * 16 + l15] = s;
        }
        __syncthreads();   // (C) sp ready; drains st loads (had full MFMA phase to fly)

        if (t < 32) {
            float s = sp[0][t] + sp[1][t] + sp[2][t] + sp[3][t]
                    + sp[4][t] + sp[5][t] + sp[6][t] + sp[7][t];
            sp2[t] = s;
            float v = s;
            v = fmaxf(v, __shfl_xor(v, 1, 32));
            v = fmaxf(v, __shfl_xor(v, 2, 32));
            v = fmaxf(v, __shfl_xor(v, 4, 32));
            v = fmaxf(v, __shfl_xor(v, 8, 32));
            v = fmaxf(v, __shfl_xor(v, 16, 32));
            if (t == 0) sp2[32] = v;
        }
        __syncthreads();   // (D) sp2 + tile-max ready

        // online softmax + PV (2 threads per column, 16 d each)
        float mn  = fmaxf(m, sp2[32]);
        float fct = fast_expf(m - mn);
        l *= fct; Ot *= fct;
        #pragma unroll 4
        for (int d = 0; d < 16; ++d) {
            int dd = dh + d;
            float w = fast_expf(sp2[dd] - mn);
            l += w;
            int byte = dd * 512 + pc * 2;
            unsigned short uv = *(const unsigned short*)((const char*)tile + (byte ^ ((dd & 7) << 4)));
            Ot += w * bf2f(uv);
        }
        m = mn;
    }

    // combine the two d-halves
    if (t >= 256) {
        spO[pc] = Ot;
        if (t == 256) spl[0] = l;
    }
    __syncthreads();
    if (t < 256) {
        float o = Ot + spO[t];
        pO[((size_t)(b * NCHK + chunk)) * HD + t] = o;
        if (t == 0) {
            pstats[(b * NCHK + chunk) * 2]     = m;
            pstats[(b * NCHK + chunk) * 2 + 1] = l + spl[0];
        }
    }
}

// ---------------- kernel 2: combine 8 chunk-partials per batch ----------------
__global__ __launch_bounds__(256) void k_comb(const float* __restrict__ pstats,
                                              const float* __restrict__ pO,
                                              float* __restrict__ out) {
    int b = blockIdx.x, t = threadIdx.x;
    float M = -1e30f;
    #pragma unroll
    for (int c = 0; c < NCHK; ++c) M = fmaxf(M, pstats[(b * NCHK + c) * 2]);
    float L = 0.f, s = 0.f;
    #pragma unroll
    for (int c = 0; c < NCHK; ++c) {
        float f = fast_expf(pstats[(b * NCHK + c) * 2] - M);
        L += f * pstats[(b * NCHK + c) * 2 + 1];
        s += f * pO[((size_t)(b * NCHK + c)) * HD + t];
    }
    out[b * HD + t] = s / L;
}

extern "C" void kernel_launch(void* const* d_in, const int* in_sizes, int n_in,
                              void* d_out, int out_size, void* d_ws, size_t ws_size,
                              hipStream_t stream) {
    (void)in_sizes; (void)n_in; (void)out_size; (void)ws_size;
    const float* ctx = (const float*)d_in[0];
    const float* q   = (const float*)d_in[1];
    const float* hid = (const float*)d_in[2];
    const float* W1  = (const float*)d_in[3];
    const float* W2  = (const float*)d_in[4];
    const float* b2  = (const float*)d_in[5];
    const float* W3  = (const float*)d_in[6];
    const float* W4  = (const float*)d_in[7];
    // d_in[8] = b4: dropped (softmax shift-invariant)
    float* out = (float*)d_out;

    char* ws = (char*)d_ws;
    unsigned short* w1b = (unsigned short*)(ws);            // 131072 B
    float* g23    = (float*)(ws + 131072);                  //  65536 B
    float* pstats = (float*)(ws + 196608);                  //   4096 B
    float* pO     = (float*)(ws + 200704);                  // 524288 B

    k_prep <<<dim3(128), dim3(256), 0, stream>>>(W1, w1b, ctx, hid, W2, b2, W3, g23);
    k_fused<<<dim3(NCHK, BB), dim3(512), 0, stream>>>(q, w1b, g23, W4, pstats, pO);
    k_comb <<<dim3(BB), dim3(256), 0, stream>>>(pstats, pO, out);
}